// Round 10
// baseline (306.717 us; speedup 1.0000x reference)
//
#include <hip/hip_runtime.h>
#include <math.h>

#define B_ 2
#define C_ 36
#define H_ 512
#define W_ 512
#define K_ 9
#define HW_ (H_ * W_)
#define HW4_ (HW_ / 4)
#define ROWF4 (W_ * C_ / 4)  // float4 pitch of one image row in featT = 4608

// ---------------------------------------------------------------------------
// Transpose features [B,C,H,W] -> [B,H,W,C], v3.  (unchanged)
// ---------------------------------------------------------------------------
__global__ __launch_bounds__(256) void transpose_kernel3(const float* __restrict__ in,
                                                         float* __restrict__ out) {
  __shared__ float tile[128][37];  // 18.9 KB
  int blk = blockIdx.x;            // ((b*H + h) << 2) | strip
  int strip = blk & 3;
  int h = (blk >> 2) & (H_ - 1);
  int b = blk >> 11;
  int w0 = strip << 7;
  int tid = threadIdx.x;

  const float4* src4 = reinterpret_cast<const float4*>(in) +
                       ((size_t)b * C_ * HW_ + (size_t)h * W_ + w0) / 4;
#pragma unroll
  for (int it = 0; it < 5; ++it) {
    int idx = it * 256 + tid;  // 0..1151 = 36 c x 32 lanes
    if (idx < C_ * 32) {
      int c = idx >> 5;
      int l = idx & 31;
      float4 v = src4[(size_t)c * HW4_ + l];
      tile[4 * l + 0][c] = v.x;
      tile[4 * l + 1][c] = v.y;
      tile[4 * l + 2][c] = v.z;
      tile[4 * l + 3][c] = v.w;
    }
  }
  __syncthreads();
  float4* dst4 = reinterpret_cast<float4*>(out + (((size_t)b * H_ + h) * W_ + w0) * C_);
#pragma unroll
  for (int it = 0; it < 5; ++it) {
    int idx = it * 256 + tid;  // float4 index 0..1151 within the strip
    if (idx < 128 * 9) {
      int px = idx / 9;
      int qq = idx - 9 * px;
      dst4[idx] = make_float4(tile[px][4 * qq + 0], tile[px][4 * qq + 1],
                              tile[px][4 * qq + 2], tile[px][4 * qq + 3]);
    }
  }
}

// ---------------------------------------------------------------------------
// v12: v11 + 64-px scratch -> ONE full-wave reduce per candidate.
// v11 post-mortem: VGPR-pool law (waves/SIMD ~= 80% * floor(256/VGPR)) holds
// on 8/8 rounds; at VGPR=60 we got 12.4 waves/CU and 176us with VALUBusy 55%.
// Issue accounting: the two half-wave owner reduces were ~64% of issue slots
// at 50% lane utilization — pure exec-mask waste forced by the 32-px scratch.
// v12 doubles scratch to 64 px/wave (+13.8 KB, LDS 40.7 KB = exactly 4 WG/CU
// = 12 waves, i.e. today's measured residency — VGPR capped at 16 anyway):
//   (1) single reduce, all 64 lanes active: ~32% fewer issue slots;
//   (2) 10 GLOAD/CONSUME rounds roll back-to-back, no mid-phase reduce;
//   (3) softmax update unmasked.
// Task map: group g=ln/9 handles tasks tt=7r+g, r=0..9 (covers 0..63 exactly
// once for g<7; lane 63 (g=7) loads clamped dummies, stores suppressed).
// Offsets loaded per-j to keep VGPR <= ~64 (4 waves/SIMD tier).
// ---------------------------------------------------------------------------
__global__ __launch_bounds__(192) void eval_kernel_ks(const float* __restrict__ feat,
                                                      const float* __restrict__ offx,
                                                      const float* __restrict__ offy,
                                                      float* __restrict__ out) {
  __shared__ __align__(16) float scratch[3][64 * 36];  // per-wave gather scratch (27.6 KB)
  __shared__ __align__(16) float4 w_lds[3][64];        // per-wave bilinear weights
  __shared__ int a_lds[3][64];                         // per-wave row0-run float4 base index
  __shared__ float F_lds[C_][64];                      // center features, channel-major (9.2 KB)

  int tid = threadIdx.x;
  int wv = tid >> 6;  // wave 0..2 -> k-set {3wv, 3wv+1, 3wv+2}
  int ln = tid & 63;

  int blk = blockIdx.x;
  int region = blk & 7;  // XCD round-robin residue -> fixed 256x256 region
  int slot = blk >> 3;   // 0..1023 within region
  int b = region >> 2;
  int qd = region & 3;
  int qy = (qd >> 1) << 8;
  int qx = (qd & 1) << 8;
  int tr = slot >> 5;  // 0..31
  int tc = slot & 31;
  if (tr & 1) tc = 31 - tc;  // serpentine: consecutive blocks share halo
  int h = qy + tr * 8 + (ln >> 3);
  int w = qx + tc * 8 + (ln & 7);
  int ph = h * W_ + w;
  int p = b * HW_ + ph;

  const float4* feat4 = reinterpret_cast<const float4*>(feat);

  const float* oxb = offx + (size_t)b * K_ * HW_ + ph;
  const float* oyb = offy + (size_t)b * K_ * HW_ + ph;

  // own pixel's center features -> LDS, cooperatively: wave wv loads channel
  // quads 3wv..3wv+2 of its pixel (disjoint (c,ln) cells, no races).
  {
    const float4* myF = feat4 + (size_t)p * 9;
#pragma unroll
    for (int i = 0; i < 3; ++i) {
      int ii = 3 * wv + i;
      float4 v = myF[ii];
      F_lds[4 * ii + 0][ln] = v.x;
      F_lds[4 * ii + 1][ln] = v.y;
      F_lds[4 * ii + 2][ln] = v.z;
      F_lds[4 * ii + 3][ln] = v.w;
    }
  }
  __syncthreads();

  int g = ln / 9;      // gather group 0..7 (g==7 -> lane 63 only, stores suppressed)
  int q = ln - 9 * g;  // channel-quad within task

  float lx = (float)w;
  float ly = (float)h;

  float M = -INFINITY, den = 0.f, axs = 0.f, ays = 0.f;

  float* myScr = scratch[wv];

#define GLOAD(Lb, T)                                \
  do {                                              \
    const float4* r0_ = feat4 + a_lds[wv][(T)];     \
    (Lb)[0] = r0_[q];                               \
    (Lb)[1] = r0_[9 + q];                           \
    (Lb)[2] = r0_[ROWF4 + q];                       \
    (Lb)[3] = r0_[ROWF4 + 9 + q];                   \
  } while (0)

#define CONSUME(Lb, T, GUARD)                                                \
  do {                                                                       \
    float4 W4_ = w_lds[wv][(T)];                                             \
    float4 a4_;                                                              \
    a4_.x = W4_.x * (Lb)[0].x + W4_.y * (Lb)[1].x + W4_.z * (Lb)[2].x + W4_.w * (Lb)[3].x; \
    a4_.y = W4_.x * (Lb)[0].y + W4_.y * (Lb)[1].y + W4_.z * (Lb)[2].y + W4_.w * (Lb)[3].y; \
    a4_.z = W4_.x * (Lb)[0].z + W4_.y * (Lb)[1].z + W4_.z * (Lb)[2].z + W4_.w * (Lb)[3].z; \
    a4_.w = W4_.x * (Lb)[0].w + W4_.y * (Lb)[1].w + W4_.z * (Lb)[2].w + W4_.w * (Lb)[3].w; \
    if ((GUARD) && ln < 63) {                                                \
      *reinterpret_cast<float4*>(&myScr[(T)*36 + 4 * q]) = a4_;              \
    }                                                                        \
  } while (0)

#pragma unroll 1
  for (int j = 0; j < 3; ++j) {
    // --- meta for my task (candidate k = 3*wv + j) ---
    float ox = oxb[(3 * wv + j) * HW_];
    float oy = oyb[(3 * wv + j) * HW_];
    float rx = fminf(fmaxf(lx + ox, 0.0f), 511.0f);
    float ry = fminf(fmaxf(ly + oy, 0.0f), 511.0f);
    float gx = (rx - 255.5f) / 255.5f;
    float gy = (ry - 255.5f) / 255.5f;
    float px = (gx + 1.0f) * 0.5f * 511.0f;
    float py = (gy + 1.0f) * 0.5f * 511.0f;
    int x0 = (int)floorf(px); x0 = (x0 > 510) ? 510 : x0;
    int y0 = (int)floorf(py); y0 = (y0 > 510) ? 510 : y0;
    float wx = px - (float)x0;
    float wy = py - (float)y0;
    w_lds[wv][ln] = make_float4((1.0f - wx) * (1.0f - wy), wx * (1.0f - wy),
                                (1.0f - wx) * wy, wx * wy);
    a_lds[wv][ln] = ((b * H_ + y0) * W_ + x0) * 9;  // float4 index of row0 run
    // no barrier: producer and consumers are the SAME wave; DS ops are
    // in-order per wave.

    float4 L[2][4];  // rolling double-buffer: 8 loads outstanding max

    // --- merged gather: 10 rolling rounds cover tasks 0..63 ---
    GLOAD(L[0], (g > 63 ? 63 : g));
#pragma unroll
    for (int r = 0; r < 10; ++r) {
      if (r < 9) {
        int ttn = 7 * (r + 1) + g;
        int tn = (ttn > 63) ? 63 : ttn;
        GLOAD(L[(r + 1) & 1], tn);
      }
      int tt = 7 * r + g;
      int t = (tt > 63) ? 63 : tt;
      CONSUME(L[r & 1], t, tt < 64);
    }

    // --- full-wave owner reduce + softmax: lane ln owns pixel ln ---
    {
      float D[9] = {0.f, 0.f, 0.f, 0.f, 0.f, 0.f, 0.f, 0.f, 0.f};
      const float4* sc = reinterpret_cast<const float4*>(&myScr[ln * 36]);
#pragma unroll
      for (int q2 = 0; q2 < 9; ++q2) {
        float4 a4 = sc[q2];
        float av[4] = {a4.x, a4.y, a4.z, a4.w};
        int ga = q2 / 3;
        int f0 = 4 * (q2 % 3);
#pragma unroll
        for (int jj = 0; jj < 4; ++jj) {
          D[ga]     += fabsf(F_lds[f0 + jj][ln]      - av[jj]);
          D[3 + ga] += fabsf(F_lds[12 + f0 + jj][ln] - av[jj]);
          D[6 + ga] += fabsf(F_lds[24 + f0 + jj][ln] - av[jj]);
        }
      }
      float mn = D[0];
#pragma unroll
      for (int jj = 1; jj < 9; ++jj) mn = fminf(mn, D[jj]);
      float xk = -(mn / 12.0f) * 1000.0f;
      float nm = fmaxf(M, xk);
      float scl = expf(M - nm);
      float ek = expf(xk - nm);
      den = den * scl + ek;
      axs = axs * scl + ox * ek;
      ays = ays * scl + oy * ek;
      M = nm;
    }
  }
#undef GLOAD
#undef CONSUME

  // --- merge the 3 waves' partial softmax states (each lane owns pixel ln) ---
  *reinterpret_cast<float4*>(&myScr[ln * 4]) = make_float4(M, den, axs, ays);
  __syncthreads();
  if (wv == 0) {
    float4 s0 = *reinterpret_cast<const float4*>(&scratch[0][ln * 4]);
    float4 s1 = *reinterpret_cast<const float4*>(&scratch[1][ln * 4]);
    float4 s2 = *reinterpret_cast<const float4*>(&scratch[2][ln * 4]);
    float nm = fmaxf(s0.x, fmaxf(s1.x, s2.x));
    float e0 = expf(s0.x - nm);
    float e1 = expf(s1.x - nm);
    float e2 = expf(s2.x - nm);
    float dent = s0.y * e0 + s1.y * e1 + s2.y * e2;
    float ax = s0.z * e0 + s1.z * e1 + s2.z * e2;
    float ay = s0.w * e0 + s1.w * e1 + s2.w * e2;
    float resx = ax / dent;
    float resy = ay / dent;
    out[p] = fminf(fmaxf(resx + lx, 0.0f), 511.0f) - lx;
    out[B_ * HW_ + p] = fminf(fmaxf(resy + ly, 0.0f), 511.0f) - ly;
  }
}

// Fallback (no scratch): original channel-major layout, thread-per-pixel.
__global__ __launch_bounds__(256) void eval_kernel_n(const float* __restrict__ feat,
                                                     const float* __restrict__ offx,
                                                     const float* __restrict__ offy,
                                                     float* __restrict__ out) {
  int p = blockIdx.x * 256 + threadIdx.x;
  int ph = p & (HW_ - 1);
  int b = p >> 18;
  float F[C_];
  const float* fb = feat + (size_t)b * C_ * HW_ + ph;
#pragma unroll
  for (int c = 0; c < C_; ++c) F[c] = fb[(size_t)c * HW_];
  float lx = (float)(ph & (W_ - 1));
  float ly = (float)((ph >> 9) & (H_ - 1));
  const float* oxb = offx + (size_t)b * K_ * HW_ + ph;
  const float* oyb = offy + (size_t)b * K_ * HW_ + ph;
  float M = -INFINITY, den = 0.f, ax = 0.f, ay = 0.f;
#pragma unroll 1
  for (int k = 0; k < K_; ++k) {
    float ox = oxb[k * HW_];
    float oy = oyb[k * HW_];
    float rx = fminf(fmaxf(lx + ox, 0.0f), 511.0f);
    float ry = fminf(fmaxf(ly + oy, 0.0f), 511.0f);
    float gx = (rx - 255.5f) / 255.5f;
    float gy = (ry - 255.5f) / 255.5f;
    float px = (gx + 1.0f) * 0.5f * 511.0f;
    float py = (gy + 1.0f) * 0.5f * 511.0f;
    int x0 = (int)floorf(px); x0 = (x0 > 510) ? 510 : x0;
    int y0 = (int)floorf(py); y0 = (y0 > 510) ? 510 : y0;
    float wx = px - (float)x0;
    float wy = py - (float)y0;
    float w00 = (1.0f - wx) * (1.0f - wy);
    float w01 = wx * (1.0f - wy);
    float w10 = (1.0f - wx) * wy;
    float w11 = wx * wy;
    float D[9] = {0.f, 0.f, 0.f, 0.f, 0.f, 0.f, 0.f, 0.f, 0.f};
    const float* pl = feat + (size_t)b * C_ * HW_ + (size_t)y0 * W_ + x0;
#pragma unroll
    for (int c = 0; c < C_; ++c) {
      const float* q0 = pl + (size_t)c * HW_;
      float v00 = q0[0], v01 = q0[1];
      float v10 = q0[W_], v11 = q0[W_ + 1];
      float a = v00 * w00 + v01 * w01 + v10 * w10 + v11 * w11;
      int i = c % 12;
      int ga = c / 12;
      D[ga]     += fabsf(F[i]      - a);
      D[3 + ga] += fabsf(F[12 + i] - a);
      D[6 + ga] += fabsf(F[24 + i] - a);
    }
    float mn = D[0];
#pragma unroll
    for (int j = 1; j < 9; ++j) mn = fminf(mn, D[j]);
    float xk = -(mn / 12.0f) * 1000.0f;
    float nm = fmaxf(M, xk);
    float sc = expf(M - nm);
    float ek = expf(xk - nm);
    den = den * sc + ek;
    ax = ax * sc + ox * ek;
    ay = ay * sc + oy * ek;
    M = nm;
  }
  float resx = ax / den;
  float resy = ay / den;
  out[p] = fminf(fmaxf(resx + lx, 0.0f), 511.0f) - lx;
  out[B_ * HW_ + p] = fminf(fmaxf(resy + ly, 0.0f), 511.0f) - ly;
}

extern "C" void kernel_launch(void* const* d_in, const int* in_sizes, int n_in,
                              void* d_out, int out_size, void* d_ws, size_t ws_size,
                              hipStream_t stream) {
  const float* features = (const float*)d_in[0];
  const float* offset_x = (const float*)d_in[1];
  const float* offset_y = (const float*)d_in[2];
  float* out = (float*)d_out;

  const int npix = B_ * HW_;  // 524288
  const size_t need = (size_t)npix * C_ * sizeof(float);  // 75.5 MB

  if (ws_size >= need) {
    float* featT = (float*)d_ws;
    transpose_kernel3<<<B_ * H_ * 4, 256, 0, stream>>>(features, featT);
    eval_kernel_ks<<<npix / 64, 192, 0, stream>>>(featT, offset_x, offset_y, out);
  } else {
    eval_kernel_n<<<npix / 256, 256, 0, stream>>>(features, offset_x, offset_y, out);
  }
}

// Round 11
// 305.715 us; speedup vs baseline: 1.0033x; 1.0033x over previous
//
#include <hip/hip_runtime.h>
#include <math.h>

#define B_ 2
#define C_ 36
#define H_ 512
#define W_ 512
#define K_ 9
#define HW_ (H_ * W_)
#define HW4_ (HW_ / 4)
#define ROWF4 (W_ * C_ / 4)  // float4 pitch of one image row in featT = 4608

// ---------------------------------------------------------------------------
// Transpose features [B,C,H,W] -> [B,H,W,C], v4: HBM channel-aliasing fix.
// v1/v2/v3 all ran ~125us (1.2 TB/s) despite 8x block-count and 4x width
// differences — because all three issue 10..36 CONCURRENT read streams at
// exactly c*1MiB stride per wave, aliasing the HBM channel interleave (every
// stream lands on the same channel; the wave serializes on it).  v4: one
// wave owns (b, 4-row band, 64w strip); per channel the wave's 4 concurrent
// 256B chunks are 4 DIFFERENT ROWS (2KiB apart -> different channels), and
// unroll-4 caps same-channel concurrency at 4 (vs 10-36).  Writes are
// contiguous 9KB runs per row.  LDS float4 tile[36][65] (+65 pad: output
// reads 4-way instead of 8-way conflicted).
// ---------------------------------------------------------------------------
__global__ __launch_bounds__(64) void transpose_kernel4(const float* __restrict__ in,
                                                        float* __restrict__ out) {
  __shared__ float4 tile[C_][65];  // [c][row*16+wq], 37.4 KB
  int blk = blockIdx.x;            // (b*128 + h4)*8 + ws
  int ws = blk & 7;
  int h4 = (blk >> 3) & 127;
  int b = blk >> 10;
  int w0 = ws << 6;
  int ln = threadIdx.x;
  int row = ln >> 4;  // 0..3
  int wq = ln & 15;   // float4 index within the 64w strip
  int h = (h4 << 2) + row;

  const float4* src4 = reinterpret_cast<const float4*>(in);
  size_t rbase = (size_t)b * C_ * HW4_ + (size_t)h * (W_ / 4) + (w0 >> 2) + wq;
#pragma unroll 4
  for (int c = 0; c < C_; ++c) {
    tile[c][ln] = src4[rbase + (size_t)c * HW4_];
  }
  __syncthreads();  // single wave; cheap, guards LDS RAW against reordering

  float4* dst4 = reinterpret_cast<float4*>(out) +
                 (((size_t)b * H_ + (size_t)(h4 << 2)) * W_ + w0) * 9 / 4 * 4 / 4;
  // NOTE: (((b*H + 4*h4)*W + w0) * C_) / 4  — computed cleanly below instead:
  dst4 = reinterpret_cast<float4*>(out + (((size_t)b * H_ + (size_t)(h4 << 2)) * W_ + w0) * C_);
#pragma unroll
  for (int r = 0; r < 4; ++r) {
#pragma unroll
    for (int it = 0; it < 9; ++it) {
      int idx = it * 64 + ln;  // 0..575 float4 within this row's 64px*36c run
      int px = idx / 9;
      int qq = idx - 9 * px;
      int s = r * 16 + (px >> 2);
      int comp = px & 3;
      float4 v;
      v.x = reinterpret_cast<const float*>(&tile[4 * qq + 0][s])[comp];
      v.y = reinterpret_cast<const float*>(&tile[4 * qq + 1][s])[comp];
      v.z = reinterpret_cast<const float*>(&tile[4 * qq + 2][s])[comp];
      v.w = reinterpret_cast<const float*>(&tile[4 * qq + 3][s])[comp];
      dst4[(size_t)r * ROWF4 + idx] = v;
    }
  }
}

// ---------------------------------------------------------------------------
// v12 eval (byte-identical to round 10's measured kernel; 174.8us, occ 31%,
// VGPR 68, no spill).  Bound at ~80% of the fitted L1-line-service ceiling
// (~0.65 lines/cyc/CU) — left unchanged this round for clean attribution of
// the transpose experiment.
// ---------------------------------------------------------------------------
__global__ __launch_bounds__(192) void eval_kernel_ks(const float* __restrict__ feat,
                                                      const float* __restrict__ offx,
                                                      const float* __restrict__ offy,
                                                      float* __restrict__ out) {
  __shared__ __align__(16) float scratch[3][64 * 36];  // per-wave gather scratch (27.6 KB)
  __shared__ __align__(16) float4 w_lds[3][64];        // per-wave bilinear weights
  __shared__ int a_lds[3][64];                         // per-wave row0-run float4 base index
  __shared__ float F_lds[C_][64];                      // center features, channel-major (9.2 KB)

  int tid = threadIdx.x;
  int wv = tid >> 6;  // wave 0..2 -> k-set {3wv, 3wv+1, 3wv+2}
  int ln = tid & 63;

  int blk = blockIdx.x;
  int region = blk & 7;  // XCD round-robin residue -> fixed 256x256 region
  int slot = blk >> 3;   // 0..1023 within region
  int b = region >> 2;
  int qd = region & 3;
  int qy = (qd >> 1) << 8;
  int qx = (qd & 1) << 8;
  int tr = slot >> 5;  // 0..31
  int tc = slot & 31;
  if (tr & 1) tc = 31 - tc;  // serpentine: consecutive blocks share halo
  int h = qy + tr * 8 + (ln >> 3);
  int w = qx + tc * 8 + (ln & 7);
  int ph = h * W_ + w;
  int p = b * HW_ + ph;

  const float4* feat4 = reinterpret_cast<const float4*>(feat);

  const float* oxb = offx + (size_t)b * K_ * HW_ + ph;
  const float* oyb = offy + (size_t)b * K_ * HW_ + ph;

  // own pixel's center features -> LDS, cooperatively: wave wv loads channel
  // quads 3wv..3wv+2 of its pixel (disjoint (c,ln) cells, no races).
  {
    const float4* myF = feat4 + (size_t)p * 9;
#pragma unroll
    for (int i = 0; i < 3; ++i) {
      int ii = 3 * wv + i;
      float4 v = myF[ii];
      F_lds[4 * ii + 0][ln] = v.x;
      F_lds[4 * ii + 1][ln] = v.y;
      F_lds[4 * ii + 2][ln] = v.z;
      F_lds[4 * ii + 3][ln] = v.w;
    }
  }
  __syncthreads();

  int g = ln / 9;      // gather group 0..7 (g==7 -> lane 63 only, stores suppressed)
  int q = ln - 9 * g;  // channel-quad within task

  float lx = (float)w;
  float ly = (float)h;

  float M = -INFINITY, den = 0.f, axs = 0.f, ays = 0.f;

  float* myScr = scratch[wv];

#define GLOAD(Lb, T)                                \
  do {                                              \
    const float4* r0_ = feat4 + a_lds[wv][(T)];     \
    (Lb)[0] = r0_[q];                               \
    (Lb)[1] = r0_[9 + q];                           \
    (Lb)[2] = r0_[ROWF4 + q];                       \
    (Lb)[3] = r0_[ROWF4 + 9 + q];                   \
  } while (0)

#define CONSUME(Lb, T, GUARD)                                                \
  do {                                                                       \
    float4 W4_ = w_lds[wv][(T)];                                             \
    float4 a4_;                                                              \
    a4_.x = W4_.x * (Lb)[0].x + W4_.y * (Lb)[1].x + W4_.z * (Lb)[2].x + W4_.w * (Lb)[3].x; \
    a4_.y = W4_.x * (Lb)[0].y + W4_.y * (Lb)[1].y + W4_.z * (Lb)[2].y + W4_.w * (Lb)[3].y; \
    a4_.z = W4_.x * (Lb)[0].z + W4_.y * (Lb)[1].z + W4_.z * (Lb)[2].z + W4_.w * (Lb)[3].z; \
    a4_.w = W4_.x * (Lb)[0].w + W4_.y * (Lb)[1].w + W4_.z * (Lb)[2].w + W4_.w * (Lb)[3].w; \
    if ((GUARD) && ln < 63) {                                                \
      *reinterpret_cast<float4*>(&myScr[(T)*36 + 4 * q]) = a4_;              \
    }                                                                        \
  } while (0)

#pragma unroll 1
  for (int j = 0; j < 3; ++j) {
    // --- meta for my task (candidate k = 3*wv + j) ---
    float ox = oxb[(3 * wv + j) * HW_];
    float oy = oyb[(3 * wv + j) * HW_];
    float rx = fminf(fmaxf(lx + ox, 0.0f), 511.0f);
    float ry = fminf(fmaxf(ly + oy, 0.0f), 511.0f);
    float gx = (rx - 255.5f) / 255.5f;
    float gy = (ry - 255.5f) / 255.5f;
    float px = (gx + 1.0f) * 0.5f * 511.0f;
    float py = (gy + 1.0f) * 0.5f * 511.0f;
    int x0 = (int)floorf(px); x0 = (x0 > 510) ? 510 : x0;
    int y0 = (int)floorf(py); y0 = (y0 > 510) ? 510 : y0;
    float wx = px - (float)x0;
    float wy = py - (float)y0;
    w_lds[wv][ln] = make_float4((1.0f - wx) * (1.0f - wy), wx * (1.0f - wy),
                                (1.0f - wx) * wy, wx * wy);
    a_lds[wv][ln] = ((b * H_ + y0) * W_ + x0) * 9;  // float4 index of row0 run
    // no barrier: producer and consumers are the SAME wave; DS ops are
    // in-order per wave.

    float4 L[2][4];  // rolling double-buffer: 8 loads outstanding max

    // --- merged gather: 10 rolling rounds cover tasks 0..63 ---
    GLOAD(L[0], (g > 63 ? 63 : g));
#pragma unroll
    for (int r = 0; r < 10; ++r) {
      if (r < 9) {
        int ttn = 7 * (r + 1) + g;
        int tn = (ttn > 63) ? 63 : ttn;
        GLOAD(L[(r + 1) & 1], tn);
      }
      int tt = 7 * r + g;
      int t = (tt > 63) ? 63 : tt;
      CONSUME(L[r & 1], t, tt < 64);
    }

    // --- full-wave owner reduce + softmax: lane ln owns pixel ln ---
    {
      float D[9] = {0.f, 0.f, 0.f, 0.f, 0.f, 0.f, 0.f, 0.f, 0.f};
      const float4* sc = reinterpret_cast<const float4*>(&myScr[ln * 36]);
#pragma unroll
      for (int q2 = 0; q2 < 9; ++q2) {
        float4 a4 = sc[q2];
        float av[4] = {a4.x, a4.y, a4.z, a4.w};
        int ga = q2 / 3;
        int f0 = 4 * (q2 % 3);
#pragma unroll
        for (int jj = 0; jj < 4; ++jj) {
          D[ga]     += fabsf(F_lds[f0 + jj][ln]      - av[jj]);
          D[3 + ga] += fabsf(F_lds[12 + f0 + jj][ln] - av[jj]);
          D[6 + ga] += fabsf(F_lds[24 + f0 + jj][ln] - av[jj]);
        }
      }
      float mn = D[0];
#pragma unroll
      for (int jj = 1; jj < 9; ++jj) mn = fminf(mn, D[jj]);
      float xk = -(mn / 12.0f) * 1000.0f;
      float nm = fmaxf(M, xk);
      float scl = expf(M - nm);
      float ek = expf(xk - nm);
      den = den * scl + ek;
      axs = axs * scl + ox * ek;
      ays = ays * scl + oy * ek;
      M = nm;
    }
  }
#undef GLOAD
#undef CONSUME

  // --- merge the 3 waves' partial softmax states (each lane owns pixel ln) ---
  *reinterpret_cast<float4*>(&myScr[ln * 4]) = make_float4(M, den, axs, ays);
  __syncthreads();
  if (wv == 0) {
    float4 s0 = *reinterpret_cast<const float4*>(&scratch[0][ln * 4]);
    float4 s1 = *reinterpret_cast<const float4*>(&scratch[1][ln * 4]);
    float4 s2 = *reinterpret_cast<const float4*>(&scratch[2][ln * 4]);
    float nm = fmaxf(s0.x, fmaxf(s1.x, s2.x));
    float e0 = expf(s0.x - nm);
    float e1 = expf(s1.x - nm);
    float e2 = expf(s2.x - nm);
    float dent = s0.y * e0 + s1.y * e1 + s2.y * e2;
    float ax = s0.z * e0 + s1.z * e1 + s2.z * e2;
    float ay = s0.w * e0 + s1.w * e1 + s2.w * e2;
    float resx = ax / dent;
    float resy = ay / dent;
    out[p] = fminf(fmaxf(resx + lx, 0.0f), 511.0f) - lx;
    out[B_ * HW_ + p] = fminf(fmaxf(resy + ly, 0.0f), 511.0f) - ly;
  }
}

// Fallback (no scratch): original channel-major layout, thread-per-pixel.
__global__ __launch_bounds__(256) void eval_kernel_n(const float* __restrict__ feat,
                                                     const float* __restrict__ offx,
                                                     const float* __restrict__ offy,
                                                     float* __restrict__ out) {
  int p = blockIdx.x * 256 + threadIdx.x;
  int ph = p & (HW_ - 1);
  int b = p >> 18;
  float F[C_];
  const float* fb = feat + (size_t)b * C_ * HW_ + ph;
#pragma unroll
  for (int c = 0; c < C_; ++c) F[c] = fb[(size_t)c * HW_];
  float lx = (float)(ph & (W_ - 1));
  float ly = (float)((ph >> 9) & (H_ - 1));
  const float* oxb = offx + (size_t)b * K_ * HW_ + ph;
  const float* oyb = offy + (size_t)b * K_ * HW_ + ph;
  float M = -INFINITY, den = 0.f, ax = 0.f, ay = 0.f;
#pragma unroll 1
  for (int k = 0; k < K_; ++k) {
    float ox = oxb[k * HW_];
    float oy = oyb[k * HW_];
    float rx = fminf(fmaxf(lx + ox, 0.0f), 511.0f);
    float ry = fminf(fmaxf(ly + oy, 0.0f), 511.0f);
    float gx = (rx - 255.5f) / 255.5f;
    float gy = (ry - 255.5f) / 255.5f;
    float px = (gx + 1.0f) * 0.5f * 511.0f;
    float py = (gy + 1.0f) * 0.5f * 511.0f;
    int x0 = (int)floorf(px); x0 = (x0 > 510) ? 510 : x0;
    int y0 = (int)floorf(py); y0 = (y0 > 510) ? 510 : y0;
    float wx = px - (float)x0;
    float wy = py - (float)y0;
    float w00 = (1.0f - wx) * (1.0f - wy);
    float w01 = wx * (1.0f - wy);
    float w10 = (1.0f - wx) * wy;
    float w11 = wx * wy;
    float D[9] = {0.f, 0.f, 0.f, 0.f, 0.f, 0.f, 0.f, 0.f, 0.f};
    const float* pl = feat + (size_t)b * C_ * HW_ + (size_t)y0 * W_ + x0;
#pragma unroll
    for (int c = 0; c < C_; ++c) {
      const float* q0 = pl + (size_t)c * HW_;
      float v00 = q0[0], v01 = q0[1];
      float v10 = q0[W_], v11 = q0[W_ + 1];
      float a = v00 * w00 + v01 * w01 + v10 * w10 + v11 * w11;
      int i = c % 12;
      int ga = c / 12;
      D[ga]     += fabsf(F[i]      - a);
      D[3 + ga] += fabsf(F[12 + i] - a);
      D[6 + ga] += fabsf(F[24 + i] - a);
    }
    float mn = D[0];
#pragma unroll
    for (int j = 1; j < 9; ++j) mn = fminf(mn, D[j]);
    float xk = -(mn / 12.0f) * 1000.0f;
    float nm = fmaxf(M, xk);
    float sc = expf(M - nm);
    float ek = expf(xk - nm);
    den = den * sc + ek;
    ax = ax * sc + ox * ek;
    ay = ay * sc + oy * ek;
    M = nm;
  }
  float resx = ax / den;
  float resy = ay / den;
  out[p] = fminf(fmaxf(resx + lx, 0.0f), 511.0f) - lx;
  out[B_ * HW_ + p] = fminf(fmaxf(resy + ly, 0.0f), 511.0f) - ly;
}

extern "C" void kernel_launch(void* const* d_in, const int* in_sizes, int n_in,
                              void* d_out, int out_size, void* d_ws, size_t ws_size,
                              hipStream_t stream) {
  const float* features = (const float*)d_in[0];
  const float* offset_x = (const float*)d_in[1];
  const float* offset_y = (const float*)d_in[2];
  float* out = (float*)d_out;

  const int npix = B_ * HW_;  // 524288
  const size_t need = (size_t)npix * C_ * sizeof(float);  // 75.5 MB

  if (ws_size >= need) {
    float* featT = (float*)d_ws;
    transpose_kernel4<<<B_ * (H_ / 4) * (W_ / 64), 64, 0, stream>>>(features, featT);
    eval_kernel_ks<<<npix / 64, 192, 0, stream>>>(featT, offset_x, offset_y, out);
  } else {
    eval_kernel_n<<<npix / 256, 256, 0, stream>>>(features, offset_x, offset_y, out);
  }
}

// Round 13
// 305.020 us; speedup vs baseline: 1.0056x; 1.0023x over previous
//
#include <hip/hip_runtime.h>
#include <math.h>

#define B_ 2
#define C_ 36
#define H_ 512
#define W_ 512
#define K_ 9
#define HW_ (H_ * W_)
#define HW4_ (HW_ / 4)
#define ROWF4 (W_ * C_ / 4)  // float4 pitch of one image row in featT = 4608

// ---------------------------------------------------------------------------
// Transpose features [B,C,H,W] -> [B,H,W,C], v4 (round-11 verified).
// ---------------------------------------------------------------------------
__global__ __launch_bounds__(64) void transpose_kernel4(const float* __restrict__ in,
                                                        float* __restrict__ out) {
  __shared__ float4 tile[C_][65];  // [c][row*16+wq], 37.4 KB
  int blk = blockIdx.x;            // (b*128 + h4)*8 + ws
  int ws = blk & 7;
  int h4 = (blk >> 3) & 127;
  int b = blk >> 10;
  int w0 = ws << 6;
  int ln = threadIdx.x;
  int row = ln >> 4;  // 0..3
  int wq = ln & 15;   // float4 index within the 64w strip
  int h = (h4 << 2) + row;

  const float4* src4 = reinterpret_cast<const float4*>(in);
  size_t rbase = (size_t)b * C_ * HW4_ + (size_t)h * (W_ / 4) + (w0 >> 2) + wq;
#pragma unroll 4
  for (int c = 0; c < C_; ++c) {
    tile[c][ln] = src4[rbase + (size_t)c * HW4_];
  }
  __syncthreads();

  float4* dst4 =
      reinterpret_cast<float4*>(out + (((size_t)b * H_ + (size_t)(h4 << 2)) * W_ + w0) * C_);
#pragma unroll
  for (int r = 0; r < 4; ++r) {
#pragma unroll
    for (int it = 0; it < 9; ++it) {
      int idx = it * 64 + ln;  // 0..575 float4 within this row's 64px*36c run
      int px = idx / 9;
      int qq = idx - 9 * px;
      int s = r * 16 + (px >> 2);
      int comp = px & 3;
      float4 v;
      v.x = reinterpret_cast<const float*>(&tile[4 * qq + 0][s])[comp];
      v.y = reinterpret_cast<const float*>(&tile[4 * qq + 1][s])[comp];
      v.z = reinterpret_cast<const float*>(&tile[4 * qq + 2][s])[comp];
      v.w = reinterpret_cast<const float*>(&tile[4 * qq + 3][s])[comp];
      dst4[(size_t)r * ROWF4 + idx] = v;
    }
  }
}

// ---------------------------------------------------------------------------
// v12 eval — byte-identical to rounds 10/11 (174.8-177us, occ 31%, VGPR 68,
// no spill; ~80% of the thrice-measured occupancy-invariant L1 line-service
// wall).  Untouched.
// ---------------------------------------------------------------------------
__global__ __launch_bounds__(192) void eval_kernel_ks(const float* __restrict__ feat,
                                                      const float* __restrict__ offx,
                                                      const float* __restrict__ offy,
                                                      float* __restrict__ out) {
  __shared__ __align__(16) float scratch[3][64 * 36];  // per-wave gather scratch (27.6 KB)
  __shared__ __align__(16) float4 w_lds[3][64];        // per-wave bilinear weights
  __shared__ int a_lds[3][64];                         // per-wave row0-run float4 base index
  __shared__ float F_lds[C_][64];                      // center features, channel-major (9.2 KB)

  int tid = threadIdx.x;
  int wv = tid >> 6;  // wave 0..2 -> k-set {3wv, 3wv+1, 3wv+2}
  int ln = tid & 63;

  int blk = blockIdx.x;
  int region = blk & 7;  // XCD round-robin residue -> fixed 256x256 region
  int slot = blk >> 3;   // 0..1023 within region
  int b = region >> 2;
  int qd = region & 3;
  int qy = (qd >> 1) << 8;
  int qx = (qd & 1) << 8;
  int tr = slot >> 5;  // 0..31
  int tc = slot & 31;
  if (tr & 1) tc = 31 - tc;  // serpentine: consecutive blocks share halo
  int h = qy + tr * 8 + (ln >> 3);
  int w = qx + tc * 8 + (ln & 7);
  int ph = h * W_ + w;
  int p = b * HW_ + ph;

  const float4* feat4 = reinterpret_cast<const float4*>(feat);

  const float* oxb = offx + (size_t)b * K_ * HW_ + ph;
  const float* oyb = offy + (size_t)b * K_ * HW_ + ph;

  // own pixel's center features -> LDS, cooperatively: wave wv loads channel
  // quads 3wv..3wv+2 of its pixel (disjoint (c,ln) cells, no races).
  {
    const float4* myF = feat4 + (size_t)p * 9;
#pragma unroll
    for (int i = 0; i < 3; ++i) {
      int ii = 3 * wv + i;
      float4 v = myF[ii];
      F_lds[4 * ii + 0][ln] = v.x;
      F_lds[4 * ii + 1][ln] = v.y;
      F_lds[4 * ii + 2][ln] = v.z;
      F_lds[4 * ii + 3][ln] = v.w;
    }
  }
  __syncthreads();

  int g = ln / 9;      // gather group 0..7 (g==7 -> lane 63 only, stores suppressed)
  int q = ln - 9 * g;  // channel-quad within task

  float lx = (float)w;
  float ly = (float)h;

  float M = -INFINITY, den = 0.f, axs = 0.f, ays = 0.f;

  float* myScr = scratch[wv];

#define GLOAD(Lb, T)                                \
  do {                                              \
    const float4* r0_ = feat4 + a_lds[wv][(T)];     \
    (Lb)[0] = r0_[q];                               \
    (Lb)[1] = r0_[9 + q];                           \
    (Lb)[2] = r0_[ROWF4 + q];                       \
    (Lb)[3] = r0_[ROWF4 + 9 + q];                   \
  } while (0)

#define CONSUME(Lb, T, GUARD)                                                \
  do {                                                                       \
    float4 W4_ = w_lds[wv][(T)];                                             \
    float4 a4_;                                                              \
    a4_.x = W4_.x * (Lb)[0].x + W4_.y * (Lb)[1].x + W4_.z * (Lb)[2].x + W4_.w * (Lb)[3].x; \
    a4_.y = W4_.x * (Lb)[0].y + W4_.y * (Lb)[1].y + W4_.z * (Lb)[2].y + W4_.w * (Lb)[3].y; \
    a4_.z = W4_.x * (Lb)[0].z + W4_.y * (Lb)[1].z + W4_.z * (Lb)[2].z + W4_.w * (Lb)[3].z; \
    a4_.w = W4_.x * (Lb)[0].w + W4_.y * (Lb)[1].w + W4_.z * (Lb)[2].w + W4_.w * (Lb)[3].w; \
    if ((GUARD) && ln < 63) {                                                \
      *reinterpret_cast<float4*>(&myScr[(T)*36 + 4 * q]) = a4_;              \
    }                                                                        \
  } while (0)

#pragma unroll 1
  for (int j = 0; j < 3; ++j) {
    // --- meta for my task (candidate k = 3*wv + j) ---
    float ox = oxb[(3 * wv + j) * HW_];
    float oy = oyb[(3 * wv + j) * HW_];
    float rx = fminf(fmaxf(lx + ox, 0.0f), 511.0f);
    float ry = fminf(fmaxf(ly + oy, 0.0f), 511.0f);
    float gx = (rx - 255.5f) / 255.5f;
    float gy = (ry - 255.5f) / 255.5f;
    float px = (gx + 1.0f) * 0.5f * 511.0f;
    float py = (gy + 1.0f) * 0.5f * 511.0f;
    int x0 = (int)floorf(px); x0 = (x0 > 510) ? 510 : x0;
    int y0 = (int)floorf(py); y0 = (y0 > 510) ? 510 : y0;
    float wx = px - (float)x0;
    float wy = py - (float)y0;
    w_lds[wv][ln] = make_float4((1.0f - wx) * (1.0f - wy), wx * (1.0f - wy),
                                (1.0f - wx) * wy, wx * wy);
    a_lds[wv][ln] = ((b * H_ + y0) * W_ + x0) * 9;  // float4 index of row0 run
    // no barrier: producer and consumers are the SAME wave; DS ops are
    // in-order per wave.

    float4 L[2][4];  // rolling double-buffer: 8 loads outstanding max

    // --- merged gather: 10 rolling rounds cover tasks 0..63 ---
    GLOAD(L[0], (g > 63 ? 63 : g));
#pragma unroll
    for (int r = 0; r < 10; ++r) {
      if (r < 9) {
        int ttn = 7 * (r + 1) + g;
        int tn = (ttn > 63) ? 63 : ttn;
        GLOAD(L[(r + 1) & 1], tn);
      }
      int tt = 7 * r + g;
      int t = (tt > 63) ? 63 : tt;
      CONSUME(L[r & 1], t, tt < 64);
    }

    // --- full-wave owner reduce + softmax: lane ln owns pixel ln ---
    {
      float D[9] = {0.f, 0.f, 0.f, 0.f, 0.f, 0.f, 0.f, 0.f, 0.f};
      const float4* sc = reinterpret_cast<const float4*>(&myScr[ln * 36]);
#pragma unroll
      for (int q2 = 0; q2 < 9; ++q2) {
        float4 a4 = sc[q2];
        float av[4] = {a4.x, a4.y, a4.z, a4.w};
        int ga = q2 / 3;
        int f0 = 4 * (q2 % 3);
#pragma unroll
        for (int jj = 0; jj < 4; ++jj) {
          D[ga]     += fabsf(F_lds[f0 + jj][ln]      - av[jj]);
          D[3 + ga] += fabsf(F_lds[12 + f0 + jj][ln] - av[jj]);
          D[6 + ga] += fabsf(F_lds[24 + f0 + jj][ln] - av[jj]);
        }
      }
      float mn = D[0];
#pragma unroll
      for (int jj = 1; jj < 9; ++jj) mn = fminf(mn, D[jj]);
      float xk = -(mn / 12.0f) * 1000.0f;
      float nm = fmaxf(M, xk);
      float scl = expf(M - nm);
      float ek = expf(xk - nm);
      den = den * scl + ek;
      axs = axs * scl + ox * ek;
      ays = ays * scl + oy * ek;
      M = nm;
    }
  }
#undef GLOAD
#undef CONSUME

  // --- merge the 3 waves' partial softmax states (each lane owns pixel ln) ---
  *reinterpret_cast<float4*>(&myScr[ln * 4]) = make_float4(M, den, axs, ays);
  __syncthreads();
  if (wv == 0) {
    float4 s0 = *reinterpret_cast<const float4*>(&scratch[0][ln * 4]);
    float4 s1 = *reinterpret_cast<const float4*>(&scratch[1][ln * 4]);
    float4 s2 = *reinterpret_cast<const float4*>(&scratch[2][ln * 4]);
    float nm = fmaxf(s0.x, fmaxf(s1.x, s2.x));
    float e0 = expf(s0.x - nm);
    float e1 = expf(s1.x - nm);
    float e2 = expf(s2.x - nm);
    float dent = s0.y * e0 + s1.y * e1 + s2.y * e2;
    float ax = s0.z * e0 + s1.z * e1 + s2.z * e2;
    float ay = s0.w * e0 + s1.w * e1 + s2.w * e2;
    float resx = ax / dent;
    float resy = ay / dent;
    out[p] = fminf(fmaxf(resx + lx, 0.0f), 511.0f) - lx;
    out[B_ * HW_ + p] = fminf(fmaxf(resy + ly, 0.0f), 511.0f) - ly;
  }
}

// Fallback (no scratch): original channel-major layout, thread-per-pixel.
__global__ __launch_bounds__(256) void eval_kernel_n(const float* __restrict__ feat,
                                                     const float* __restrict__ offx,
                                                     const float* __restrict__ offy,
                                                     float* __restrict__ out) {
  int p = blockIdx.x * 256 + threadIdx.x;
  int ph = p & (HW_ - 1);
  int b = p >> 18;
  float F[C_];
  const float* fb = feat + (size_t)b * C_ * HW_ + ph;
#pragma unroll
  for (int c = 0; c < C_; ++c) F[c] = fb[(size_t)c * HW_];
  float lx = (float)(ph & (W_ - 1));
  float ly = (float)((ph >> 9) & (H_ - 1));
  const float* oxb = offx + (size_t)b * K_ * HW_ + ph;
  const float* oyb = offy + (size_t)b * K_ * HW_ + ph;
  float M = -INFINITY, den = 0.f, ax = 0.f, ay = 0.f;
#pragma unroll 1
  for (int k = 0; k < K_; ++k) {
    float ox = oxb[k * HW_];
    float oy = oyb[k * HW_];
    float rx = fminf(fmaxf(lx + ox, 0.0f), 511.0f);
    float ry = fminf(fmaxf(ly + oy, 0.0f), 511.0f);
    float gx = (rx - 255.5f) / 255.5f;
    float gy = (ry - 255.5f) / 255.5f;
    float px = (gx + 1.0f) * 0.5f * 511.0f;
    float py = (gy + 1.0f) * 0.5f * 511.0f;
    int x0 = (int)floorf(px); x0 = (x0 > 510) ? 510 : x0;
    int y0 = (int)floorf(py); y0 = (y0 > 510) ? 510 : y0;
    float wx = px - (float)x0;
    float wy = py - (float)y0;
    float w00 = (1.0f - wx) * (1.0f - wy);
    float w01 = wx * (1.0f - wy);
    float w10 = (1.0f - wx) * wy;
    float w11 = wx * wy;
    float D[9] = {0.f, 0.f, 0.f, 0.f, 0.f, 0.f, 0.f, 0.f, 0.f};
    const float* pl = feat + (size_t)b * C_ * HW_ + (size_t)y0 * W_ + x0;
#pragma unroll
    for (int c = 0; c < C_; ++c) {
      const float* q0 = pl + (size_t)c * HW_;
      float v00 = q0[0], v01 = q0[1];
      float v10 = q0[W_], v11 = q0[W_ + 1];
      float a = v00 * w00 + v01 * w01 + v10 * w10 + v11 * w11;
      int i = c % 12;
      int ga = c / 12;
      D[ga]     += fabsf(F[i]      - a);
      D[3 + ga] += fabsf(F[12 + i] - a);
      D[6 + ga] += fabsf(F[24 + i] - a);
    }
    float mn = D[0];
#pragma unroll
    for (int j = 1; j < 9; ++j) mn = fminf(mn, D[j]);
    float xk = -(mn / 12.0f) * 1000.0f;
    float nm = fmaxf(M, xk);
    float sc = expf(M - nm);
    float ek = expf(xk - nm);
    den = den * sc + ek;
    ax = ax * sc + ox * ek;
    ay = ay * sc + oy * ek;
    M = nm;
  }
  float resx = ax / den;
  float resy = ay / den;
  out[p] = fminf(fmaxf(resx + lx, 0.0f), 511.0f) - lx;
  out[B_ * HW_ + p] = fminf(fmaxf(resy + ly, 0.0f), 511.0f) - ly;
}

extern "C" void kernel_launch(void* const* d_in, const int* in_sizes, int n_in,
                              void* d_out, int out_size, void* d_ws, size_t ws_size,
                              hipStream_t stream) {
  const float* features = (const float*)d_in[0];
  const float* offset_x = (const float*)d_in[1];
  const float* offset_y = (const float*)d_in[2];
  float* out = (float*)d_out;

  const int npix = B_ * HW_;  // 524288
  const size_t need = (size_t)npix * C_ * sizeof(float);  // 75.5 MB

  if (ws_size >= need) {
    float* featT = (float*)d_ws;
    transpose_kernel4<<<B_ * (H_ / 4) * (W_ / 64), 64, 0, stream>>>(features, featT);
    eval_kernel_ks<<<npix / 64, 192, 0, stream>>>(featT, offset_x, offset_y, out);
  } else {
    eval_kernel_n<<<npix / 256, 256, 0, stream>>>(features, offset_x, offset_y, out);
  }
}